// Round 11
// baseline (203.541 us; speedup 1.0000x reference)
//
#include <hip/hip_runtime.h>
#include <math.h>

#define NPOS 2304   // 48*48
#define CC   256    // DIM
#define DI   512    // HEADS*DIM_HEAD
#define NT   36     // NPOS/64
#define SCALE 0.125f
#define MASKV -100.0f
// exp(-SCALE*sqrt(d2)) = exp2(-SCALE*log2(e)*sqrt(d2))
#define NEGSL2E (-0.18033688011112042f)

typedef __attribute__((ext_vector_type(8))) short bf16x8;  // 8 bf16 (4 VGPRs)
typedef __attribute__((ext_vector_type(4))) float f32x4;   // MFMA C/D frag
typedef unsigned short u16;
typedef unsigned int u32;

__device__ inline u16 f2bf(float f) {
    union { float f; unsigned int u; } v; v.f = f;
    return (u16)((v.u + 0x7fffu + ((v.u >> 16) & 1u)) >> 16);
}
__device__ inline float bf2f(u16 h) { return __uint_as_float(((u32)h) << 16); }

// assemble a bf16x8 frag from 8-byte-aligned LDS via two b64 reads
__device__ inline bf16x8 ld_x8(const u16* p) {
    union { bf16x8 v; uint2 d[2]; } u;
    u.d[0] = *(const uint2*)(p + 0);
    u.d[1] = *(const uint2*)(p + 4);
    return u.v;
}

// ---------------- Kernel 1: fused rmsnorm + MFMA qk/v projection (+ wo split) ----------------
// oy<8: qk head -> qkh + sq/ndot; oy in [8,16): v head -> vt frag-ordered;
// oy==16: one-time w_out hi/lo split (72 light blocks).
__global__ __launch_bounds__(256) void k_proj(const float* __restrict__ fmap,
                                              const float* __restrict__ gamma,
                                              const float* __restrict__ wqk,
                                              const float* __restrict__ wv,
                                              const float* __restrict__ wout,
                                              const float* __restrict__ null_kv,
                                              u16* __restrict__ qkh,
                                              u16* __restrict__ vt,
                                              float* __restrict__ sq,
                                              float* __restrict__ ndot,
                                              float* __restrict__ nk2b,
                                              u16* __restrict__ wo_hi,
                                              u16* __restrict__ wo_lo) {
    const int oy = blockIdx.y;            // 0..16
    if (oy == 16) {                       // w_out hi/lo split (no LDS, early out)
        const int idx = blockIdx.z * 36 + blockIdx.x;   // 0..71
#pragma unroll
        for (int it = 0; it < 2; ++it) {
            const int k = idx * 512 + (int)threadIdx.x + it * 256;
            if (k < 32768) {
                const float4 v = ((const float4*)wout)[k];
                ushort4 h4, l4;
                h4.x = f2bf(v.x); l4.x = f2bf(v.x - bf2f(h4.x));
                h4.y = f2bf(v.y); l4.y = f2bf(v.y - bf2f(h4.y));
                h4.z = f2bf(v.z); l4.z = f2bf(v.z - bf2f(h4.z));
                h4.w = f2bf(v.w); l4.w = f2bf(v.w - bf2f(h4.w));
                ((ushort4*)wo_hi)[k] = h4;
                ((ushort4*)wo_lo)[k] = l4;
            }
        }
        return;
    }
    const int n0 = blockIdx.x * 64;
    const int b  = blockIdx.z;
    const int t  = threadIdx.x;
    const int w = t >> 6, lane = t & 63, mcol = lane & 15, quad = lane >> 4;
    const int tx = t & 63, ty = t >> 6;

    __shared__ u16 X[64][260];            // [pos][chan]; dword pitch 130 (==2 mod 32), rows 8B-aligned
    __shared__ float red[4][64];
    __shared__ float inv_s[64];
    __shared__ float gs[256];
    __shared__ float sqp[4][64], ndp[4][64];
    u16 (*Tt)[68] = (u16(*)[68])X;        // aliased after phase B

    // ---- phase A: rmsnorm ----
    gs[t] = gamma[t];
    const float* fb = fmap + (size_t)b * CC * NPOS;
    float s = 0.0f;
#pragma unroll 8
    for (int i = 0; i < 64; ++i) {
        const int c = ty * 64 + i;
        const float v = fb[c * NPOS + n0 + tx];
        s += v * v;
    }
    red[ty][tx] = s;
    __syncthreads();
    if (t < 64) {
        const float tt = red[0][t] + red[1][t] + red[2][t] + red[3][t];
        inv_s[t] = 16.0f / fmaxf(sqrtf(tt), 1e-12f);
    }
    __syncthreads();
    const float iv = inv_s[tx];
#pragma unroll 4
    for (int i = 0; i < 64; i += 2) {
        const int c = ty * 64 + i;
        const float v0 = fb[c * NPOS + n0 + tx] * iv * gs[c];
        const float v1 = fb[(c + 1) * NPOS + n0 + tx] * iv * gs[c + 1];
        *(u32*)&X[tx][c] = (u32)f2bf(v0) | ((u32)f2bf(v1) << 16);   // bank 2-way: free
    }
    if (blockIdx.x == 0 && oy == 0 && b == 0 && t < 8) {
        float s2 = 0.0f;
#pragma unroll 8
        for (int d = 0; d < 64; ++d) { const float x = null_kv[t * 64 + d]; s2 += x * x; }
        nk2b[t] = s2;
    }
    __syncthreads();

    // ---- phase B: MFMA, W converted fp32->bf16 in registers ----
    const float* Wf = (oy < 8) ? wqk : wv;
    const int or0 = (oy & 7) * 64;
    const float* wr = Wf + (size_t)(or0 + w * 16 + mcol) * 256 + quad * 8;

    f32x4 c4[4];
#pragma unroll
    for (int nf = 0; nf < 4; ++nf) c4[nf] = (f32x4){0.f, 0.f, 0.f, 0.f};
#pragma unroll
    for (int kc = 0; kc < 8; ++kc) {
        const float4 wa = *(const float4*)&wr[kc * 32];
        const float4 wb4 = *(const float4*)&wr[kc * 32 + 4];
        bf16x8 a;
        a[0] = f2bf(wa.x);  a[1] = f2bf(wa.y);  a[2] = f2bf(wa.z);  a[3] = f2bf(wa.w);
        a[4] = f2bf(wb4.x); a[5] = f2bf(wb4.y); a[6] = f2bf(wb4.z); a[7] = f2bf(wb4.w);
        bf16x8 xB[4];
#pragma unroll
        for (int nf = 0; nf < 4; ++nf)
            xB[nf] = ld_x8(&X[nf * 16 + mcol][kc * 32 + quad * 8]);
#pragma unroll
        for (int nf = 0; nf < 4; ++nf)
            c4[nf] = __builtin_amdgcn_mfma_f32_16x16x32_bf16(a, xB[nf], c4[nf], 0, 0, 0);
    }
    __syncthreads();   // all X reads done; Tt alias safe

    if (oy < 8) {
        const int h = oy;   // d = w*16 + quad*4 + r, n = n0 + nf*16 + mcol
        const float4 nk4 = *(const float4*)&null_kv[h * 64 + w * 16 + quad * 4];
        float sv[4], nd[4];
#pragma unroll
        for (int nf = 0; nf < 4; ++nf) {
            sv[nf] = c4[nf][0] * c4[nf][0] + c4[nf][1] * c4[nf][1] + c4[nf][2] * c4[nf][2] + c4[nf][3] * c4[nf][3];
            nd[nf] = c4[nf][0] * nk4.x + c4[nf][1] * nk4.y + c4[nf][2] * nk4.z + c4[nf][3] * nk4.w;
        }
#pragma unroll
        for (int mk = 16; mk <= 32; mk <<= 1)
#pragma unroll
            for (int nf = 0; nf < 4; ++nf) {
                sv[nf] += __shfl_xor(sv[nf], mk);
                nd[nf] += __shfl_xor(nd[nf], mk);
            }
        if (quad == 0) {
#pragma unroll
            for (int nf = 0; nf < 4; ++nf) {
                sqp[w][nf * 16 + mcol] = sv[nf];
                ndp[w][nf * 16 + mcol] = nd[nf];
            }
        }
#pragma unroll
        for (int nf = 0; nf < 4; ++nf) {
            ushort4 r4;
            r4.x = f2bf(c4[nf][0]); r4.y = f2bf(c4[nf][1]);
            r4.z = f2bf(c4[nf][2]); r4.w = f2bf(c4[nf][3]);
            *(ushort4*)&Tt[nf * 16 + mcol][w * 16 + quad * 4] = r4;   // Tt[n][d]
        }
        __syncthreads();
        {
            const int n = t >> 2, ds = (t & 3) * 16;
            const uint2 r0 = *(const uint2*)&Tt[n][ds + 0];
            const uint2 r1 = *(const uint2*)&Tt[n][ds + 4];
            const uint2 r2 = *(const uint2*)&Tt[n][ds + 8];
            const uint2 r3 = *(const uint2*)&Tt[n][ds + 12];
            u16* dst = qkh + (((size_t)b * 8 + h) * NPOS + n0 + n) * 64 + ds;
            *(uint4*)&dst[0] = make_uint4(r0.x, r0.y, r1.x, r1.y);
            *(uint4*)&dst[8] = make_uint4(r2.x, r2.y, r3.x, r3.y);
        }
        if (t < 64) {
            sq  [((size_t)b * 8 + h) * NPOS + n0 + t] = sqp[0][t] + sqp[1][t] + sqp[2][t] + sqp[3][t];
            ndot[((size_t)b * 8 + h) * NPOS + n0 + t] = ndp[0][t] + ndp[1][t] + ndp[2][t] + ndp[3][t];
        }
    } else {
        const int h = oy - 8;   // d = w*16+quad*4+r, key = n0 + nf*16 + mcol
#pragma unroll
        for (int nf = 0; nf < 4; ++nf)
#pragma unroll
            for (int r = 0; r < 4; ++r)
                Tt[w * 16 + quad * 4 + r][nf * 16 + mcol] = f2bf(c4[nf][r]);  // Tt[d][key]
        __syncthreads();
        {
            const int d = t >> 2, ks = t & 3;
            const uint2 a0 = *(const uint2*)&Tt[d][ks * 16 + 0];
            const uint2 a1 = *(const uint2*)&Tt[d][ks * 16 + 4];
            const uint2 a2 = *(const uint2*)&Tt[d][ks * 16 + 8];
            const uint2 a3 = *(const uint2*)&Tt[d][ks * 16 + 12];
            u16* vdst = vt + (size_t)(b * 8 + h) * (72 * 64 * 32);
            const int kb = blockIdx.x * 2 + (ks >> 1);
            u16* p = &vdst[((size_t)kb * 64 + d) * 32 + (ks & 1) * 16];
            *(uint4*)&p[0] = make_uint4(a0.x, a0.y, a1.x, a1.y);
            *(uint4*)&p[8] = make_uint4(a2.x, a2.y, a3.x, a3.y);
        }
    }
}

// ---------------- Kernel 2: K-split MFMA flash attention, 32 q/wave, XCD-swizzled ----------------
// LDS = 18.4 KB (Pt region only; merge reuses it in 2 passes of 16 queries)
// -> 5 blocks/CU resident, all 1152 blocks co-resident from dispatch.
__global__ __launch_bounds__(256) void k_attn(const u16* __restrict__ qkh,
                                              const u16* __restrict__ vt,
                                              const float* __restrict__ null_kv,
                                              const float* __restrict__ nk2b,
                                              const float* __restrict__ sq,
                                              const float* __restrict__ ndot,
                                              u16* __restrict__ ih,
                                              u16* __restrict__ il) {
    const int blk = blockIdx.x;
    const int xcd = blk & 7;
    const int j = blk >> 3;                 // 0..143
    const int bh = xcd * 2 + (j & 1);       // XCD-local bh pair
    const int qb = j >> 1;                  // 0..71
    const int q32 = qb * 32;
    const int tile0 = qb * 2;
    const int b = bh >> 3, h = bh & 7;
    const int t = threadIdx.x;
    const int wave = t >> 6, lane = t & 63;
    const int mcol = lane & 15, quad = lane >> 4;

    // union: per-wave Pt[32][72] u16 (4 x 4608 B) || merge buf float[4][16][66] (16.9 KB)
    __shared__ __align__(16) char smem[18432];
    u16 (*Pt)[72] = (u16(*)[72])(smem + wave * 4608);

    const u16* qbase = qkh + (size_t)bh * NPOS * 64;
    const u16* vbase = vt + (size_t)bh * (72 * 64 * 32);
    const float* sqb = sq + (size_t)bh * NPOS;

    bf16x8 bq00, bq01, bq10, bq11;
    bq00 = *(const bf16x8*)&qbase[(q32 + mcol) * 64 + quad * 8];
    bq01 = *(const bf16x8*)&qbase[(q32 + mcol) * 64 + 32 + quad * 8];
    bq10 = *(const bf16x8*)&qbase[(q32 + 16 + mcol) * 64 + quad * 8];
    bq11 = *(const bf16x8*)&qbase[(q32 + 16 + mcol) * 64 + 32 + quad * 8];
    const float q2g0 = sqb[q32 + mcol];
    const float q2g1 = sqb[q32 + 16 + mcol];

    const bf16x8 ones = {0x3F80, 0x3F80, 0x3F80, 0x3F80, 0x3F80, 0x3F80, 0x3F80, 0x3F80};

    f32x4 oacc[2][4];
#pragma unroll
    for (int g = 0; g < 2; ++g)
#pragma unroll
        for (int nb = 0; nb < 4; ++nb) oacc[g][nb] = (f32x4){0.f, 0.f, 0.f, 0.f};
    f32x4 lsum0 = (f32x4){0.f, 0.f, 0.f, 0.f};
    f32x4 lsum1 = (f32x4){0.f, 0.f, 0.f, 0.f};

    const int kt0 = wave * 9;
#pragma unroll 2
    for (int k9 = 0; k9 < 9; ++k9) {
        const int kt = kt0 + k9;
        const int kj0 = kt * 64;

        bf16x8 bk[4][2], bv[4][2];
#pragma unroll
        for (int nb = 0; nb < 4; ++nb) {
            const u16* kr = &qbase[(kj0 + nb * 16 + mcol) * 64 + quad * 8];
            bk[nb][0] = *(const bf16x8*)&kr[0];
            bk[nb][1] = *(const bf16x8*)&kr[32];
        }
#pragma unroll
        for (int nb = 0; nb < 4; ++nb) {
            bv[nb][0] = *(const bf16x8*)&vbase[((size_t)(kt * 2 + 0) * 64 + nb * 16 + mcol) * 32 + quad * 8];
            bv[nb][1] = *(const bf16x8*)&vbase[((size_t)(kt * 2 + 1) * 64 + nb * 16 + mcol) * 32 + quad * 8];
        }
        float4 k2q[4];
#pragma unroll
        for (int nb = 0; nb < 4; ++nb)
            k2q[nb] = *(const float4*)&sqb[kj0 + nb * 16 + quad * 4];

        f32x4 c[2][4];
#pragma unroll
        for (int nb = 0; nb < 4; ++nb) {
            c[0][nb] = (f32x4){0.f, 0.f, 0.f, 0.f};
            c[0][nb] = __builtin_amdgcn_mfma_f32_16x16x32_bf16(bk[nb][0], bq00, c[0][nb], 0, 0, 0);
            c[0][nb] = __builtin_amdgcn_mfma_f32_16x16x32_bf16(bk[nb][1], bq01, c[0][nb], 0, 0, 0);
            c[1][nb] = (f32x4){0.f, 0.f, 0.f, 0.f};
            c[1][nb] = __builtin_amdgcn_mfma_f32_16x16x32_bf16(bk[nb][0], bq10, c[1][nb], 0, 0, 0);
            c[1][nb] = __builtin_amdgcn_mfma_f32_16x16x32_bf16(bk[nb][1], bq11, c[1][nb], 0, 0, 0);
        }

#pragma unroll
        for (int g = 0; g < 2; ++g) {
            const float q2 = g ? q2g1 : q2g0;
            const int ktm = (tile0 + g) >> 2, nbm = (tile0 + g) & 3;
#pragma unroll
            for (int nb = 0; nb < 4; ++nb) {
                float e[4];
#pragma unroll
                for (int r = 0; r < 4; ++r) {
                    const float pre = q2 + ((const float*)&k2q[nb])[r];
                    const float d2 = fmaxf(__builtin_fmaf(c[g][nb][r], -2.0f, pre), 0.0f);
                    e[r] = __builtin_amdgcn_exp2f(NEGSL2E * __builtin_amdgcn_sqrtf(d2));
                }
                if (kt == ktm && nb == nbm) {
#pragma unroll
                    for (int r = 0; r < 4; ++r)
                        if (quad * 4 + r == mcol) e[r] = 0.0f;   // exp(MASKV) ~ 0
                }
                const u32 p01 = __builtin_amdgcn_perm(__float_as_uint(e[1]), __float_as_uint(e[0]), 0x07060302u);
                const u32 p23 = __builtin_amdgcn_perm(__float_as_uint(e[3]), __float_as_uint(e[2]), 0x07060302u);
                *(uint2*)&Pt[g * 16 + mcol][nb * 16 + quad * 4] = make_uint2(p01, p23);
            }
        }

        const bf16x8 bp00 = *(const bf16x8*)&Pt[mcol][quad * 8];
        const bf16x8 bp01 = *(const bf16x8*)&Pt[mcol][32 + quad * 8];
        const bf16x8 bp10 = *(const bf16x8*)&Pt[16 + mcol][quad * 8];
        const bf16x8 bp11 = *(const bf16x8*)&Pt[16 + mcol][32 + quad * 8];

#pragma unroll
        for (int nb = 0; nb < 4; ++nb) {
            oacc[0][nb] = __builtin_amdgcn_mfma_f32_16x16x32_bf16(bv[nb][0], bp00, oacc[0][nb], 0, 0, 0);
            oacc[0][nb] = __builtin_amdgcn_mfma_f32_16x16x32_bf16(bv[nb][1], bp01, oacc[0][nb], 0, 0, 0);
            oacc[1][nb] = __builtin_amdgcn_mfma_f32_16x16x32_bf16(bv[nb][0], bp10, oacc[1][nb], 0, 0, 0);
            oacc[1][nb] = __builtin_amdgcn_mfma_f32_16x16x32_bf16(bv[nb][1], bp11, oacc[1][nb], 0, 0, 0);
        }
        lsum0 = __builtin_amdgcn_mfma_f32_16x16x32_bf16(ones, bp00, lsum0, 0, 0, 0);
        lsum0 = __builtin_amdgcn_mfma_f32_16x16x32_bf16(ones, bp01, lsum0, 0, 0, 0);
        lsum1 = __builtin_amdgcn_mfma_f32_16x16x32_bf16(ones, bp10, lsum1, 0, 0, 0);
        lsum1 = __builtin_amdgcn_mfma_f32_16x16x32_bf16(ones, bp11, lsum1, 0, 0, 0);
    }

    // ---- in-block cross-wave merge, 2 passes of 16 queries (LDS stays 18.4 KB) ----
    float* Of = (float*)smem;
    float* Ow = Of + wave * (16 * 66);
#pragma unroll
    for (int p = 0; p < 2; ++p) {
        __syncthreads();   // p0: Pt reads done; p1: prev merge reads done
#pragma unroll
        for (int nb = 0; nb < 4; ++nb)
#pragma unroll
            for (int r = 0; r < 4; ++r)
                Ow[mcol * 66 + nb * 16 + quad * 4 + r] = oacc[p][nb][r];
        if (quad == 0) Ow[mcol * 66 + 64] = p ? lsum1[0] : lsum0[0];
        __syncthreads();

        const int q = t >> 4;            // 0..15
        const int d0 = (t & 15) * 4;     // 0..60
        float o[4] = {0.f, 0.f, 0.f, 0.f};
        float l = 0.0f;
#pragma unroll
        for (int w = 0; w < 4; ++w) {
            const float* src = Of + w * (16 * 66) + q * 66;
            const float4 a = *(const float4*)&src[d0];
            o[0] += a.x; o[1] += a.y; o[2] += a.z; o[3] += a.w;
            l += src[64];
        }
        const int qg = q32 + p * 16 + q;
        const float q2v = sqb[qg];
        const float nd = ndot[(size_t)bh * NPOS + qg];
        const float nk2 = nk2b[h];
        const float d2n = fmaxf(q2v + nk2 - 2.0f * nd, 0.0f);
        const float beta = __expf(-sqrtf(d2n) * SCALE);
        const float ilv = 1.0f / (l + beta);

        const float4 nv4 = *(const float4*)&null_kv[DI + h * 64 + d0];
        float v[4];
        v[0] = (o[0] + beta * nv4.x) * ilv;
        v[1] = (o[1] + beta * nv4.y) * ilv;
        v[2] = (o[2] + beta * nv4.z) * ilv;
        v[3] = (o[3] + beta * nv4.w) * ilv;
        ushort4 hi4, lo4;
        hi4.x = f2bf(v[0]); lo4.x = f2bf(v[0] - bf2f(hi4.x));
        hi4.y = f2bf(v[1]); lo4.y = f2bf(v[1] - bf2f(hi4.y));
        hi4.z = f2bf(v[2]); lo4.z = f2bf(v[2] - bf2f(hi4.z));
        hi4.w = f2bf(v[3]); lo4.w = f2bf(v[3] - bf2f(hi4.w));
        const size_t ob = ((size_t)b * NPOS + qg) * DI + h * 64 + d0;
        *(ushort4*)&ih[ob] = hi4;
        *(ushort4*)&il[ob] = lo4;
    }
}

// ---------------- Kernel 3: output projection (split-bf16 MFMA, staged W) ----------------
__global__ __launch_bounds__(256) void k_out(const u16* __restrict__ wo_hi,
                                             const u16* __restrict__ wo_lo,
                                             const u16* __restrict__ ih,
                                             const u16* __restrict__ il,
                                             float* __restrict__ out) {
    const int j0 = blockIdx.x * 64;
    const int c0 = blockIdx.y * 64;
    const int b  = blockIdx.z;
    const int t  = threadIdx.x;
    const int w = t >> 6, lane = t & 63, mcol = lane & 15, quad = lane >> 4;

    const u16* ah = wo_hi + (size_t)(c0 + w * 16 + mcol) * 512 + quad * 8;
    const u16* al = wo_lo + (size_t)(c0 + w * 16 + mcol) * 512 + quad * 8;
    const u16* xh = ih + ((size_t)b * NPOS + j0 + mcol) * 512 + quad * 8;
    const u16* xl = il + ((size_t)b * NPOS + j0 + mcol) * 512 + quad * 8;

    f32x4 c[4];
#pragma unroll
    for (int nf = 0; nf < 4; ++nf) c[nf] = (f32x4){0.f, 0.f, 0.f, 0.f};
#pragma unroll
    for (int kc = 0; kc < 16; ++kc) {
        const bf16x8 A  = *(const bf16x8*)&ah[kc * 32];
        const bf16x8 Al = *(const bf16x8*)&al[kc * 32];
        bf16x8 Bh[4], Bl[4];
#pragma unroll
        for (int nf = 0; nf < 4; ++nf) {
            Bh[nf] = *(const bf16x8*)&xh[(size_t)nf * 16 * 512 + kc * 32];
            Bl[nf] = *(const bf16x8*)&xl[(size_t)nf * 16 * 512 + kc * 32];
        }
#pragma unroll
        for (int nf = 0; nf < 4; ++nf) {
            c[nf] = __builtin_amdgcn_mfma_f32_16x16x32_bf16(A,  Bh[nf], c[nf], 0, 0, 0);
            c[nf] = __builtin_amdgcn_mfma_f32_16x16x32_bf16(A,  Bl[nf], c[nf], 0, 0, 0);
            c[nf] = __builtin_amdgcn_mfma_f32_16x16x32_bf16(Al, Bh[nf], c[nf], 0, 0, 0);
        }
    }
    float* ob = out + ((size_t)b * CC + c0 + w * 16) * NPOS + j0;
#pragma unroll
    for (int nf = 0; nf < 4; ++nf)
#pragma unroll
        for (int r = 0; r < 4; ++r)
            ob[(size_t)(quad * 4 + r) * NPOS + nf * 16 + mcol] = c[nf][r];
}

extern "C" void kernel_launch(void* const* d_in, const int* in_sizes, int n_in,
                              void* d_out, int out_size, void* d_ws, size_t ws_size,
                              hipStream_t stream) {
    const float* fmap    = (const float*)d_in[0];
    const float* gamma   = (const float*)d_in[1];
    const float* w_qk    = (const float*)d_in[2];
    const float* w_v     = (const float*)d_in[3];
    const float* null_kv = (const float*)d_in[4];
    const float* w_out   = (const float*)d_in[5];
    float* out = (float*)d_out;

    u16* ws16 = (u16*)d_ws;
    u16* qkh    = ws16;                     // 16*2304*64  = 2,359,296 u16
    u16* vtb    = qkh + 2359296;            // 16*72*64*32 = 2,359,296
    u16* in_hi  = vtb + 2359296;            // 2*2304*512  = 2,359,296
    u16* in_lo  = in_hi + 2359296;          //               2,359,296
    u16* wo_hi  = in_lo + 2359296;          // 256*512     =   131,072
    u16* wo_lo  = wo_hi + 131072;           //                 131,072
    float* sqbuf = (float*)(wo_lo + 131072);    // 36,864 f32
    float* ndbuf = sqbuf + 36864;               // 36,864
    float* nk2b  = ndbuf + 36864;               // 8
    // total ~ 19.5 MB

    hipLaunchKernelGGL(k_proj, dim3(NT, 17, 2), dim3(256), 0, stream,
                       fmap, gamma, w_qk, w_v, w_out, null_kv, qkh, vtb, sqbuf, ndbuf, nk2b, wo_hi, wo_lo);
    hipLaunchKernelGGL(k_attn, dim3(1152),      dim3(256), 0, stream,
                       qkh, vtb, null_kv, nk2b, sqbuf, ndbuf, in_hi, in_lo);
    hipLaunchKernelGGL(k_out,  dim3(NT, 4, 2),  dim3(256), 0, stream,
                       wo_hi, wo_lo, in_hi, in_lo, out);
}

// Round 12
// 194.813 us; speedup vs baseline: 1.0448x; 1.0448x over previous
//
#include <hip/hip_runtime.h>
#include <math.h>

#define NPOS 2304   // 48*48
#define CC   256    // DIM
#define DI   512    // HEADS*DIM_HEAD
#define NT   36     // NPOS/64
#define SCALE 0.125f
#define MASKV -100.0f
// exp(-SCALE*sqrt(d2)) = exp2(-SCALE*log2(e)*sqrt(d2))
#define NEGSL2E (-0.18033688011112042f)

typedef __attribute__((ext_vector_type(8))) short bf16x8;  // 8 bf16 (4 VGPRs)
typedef __attribute__((ext_vector_type(4))) float f32x4;   // MFMA C/D frag
typedef unsigned short u16;
typedef unsigned int u32;

__device__ inline u16 f2bf(float f) {
    union { float f; unsigned int u; } v; v.f = f;
    return (u16)((v.u + 0x7fffu + ((v.u >> 16) & 1u)) >> 16);
}
__device__ inline float bf2f(u16 h) { return __uint_as_float(((u32)h) << 16); }

// assemble a bf16x8 frag from 8-byte-aligned LDS via two b64 reads
__device__ inline bf16x8 ld_x8(const u16* p) {
    union { bf16x8 v; uint2 d[2]; } u;
    u.d[0] = *(const uint2*)(p + 0);
    u.d[1] = *(const uint2*)(p + 4);
    return u.v;
}

// ---------------- Kernel 1: fused rmsnorm + paired qk/v MFMA projection ----------------
// oy in [0,8): block computes BOTH head oy of qk AND head oy of v for its 64
// positions: phase A (rmsnorm, fmap held in VGPRs) runs once, X LDS frag reads
// feed both heads' MFMA. oy==8: one-time w_out hi/lo split (72 light blocks).
__global__ __launch_bounds__(256) void k_proj(const float* __restrict__ fmap,
                                              const float* __restrict__ gamma,
                                              const float* __restrict__ wqk,
                                              const float* __restrict__ wv,
                                              const float* __restrict__ wout,
                                              const float* __restrict__ null_kv,
                                              u16* __restrict__ qkh,
                                              u16* __restrict__ vt,
                                              float* __restrict__ sq,
                                              float* __restrict__ ndot,
                                              float* __restrict__ nk2b,
                                              u16* __restrict__ wo_hi,
                                              u16* __restrict__ wo_lo) {
    const int oy = blockIdx.y;            // 0..8
    if (oy == 8) {                        // w_out hi/lo split (no LDS use, early out)
        const int idx = blockIdx.z * 36 + blockIdx.x;   // 0..71
#pragma unroll
        for (int it = 0; it < 2; ++it) {
            const int k = idx * 512 + (int)threadIdx.x + it * 256;
            if (k < 32768) {
                const float4 v = ((const float4*)wout)[k];
                ushort4 h4, l4;
                h4.x = f2bf(v.x); l4.x = f2bf(v.x - bf2f(h4.x));
                h4.y = f2bf(v.y); l4.y = f2bf(v.y - bf2f(h4.y));
                h4.z = f2bf(v.z); l4.z = f2bf(v.z - bf2f(h4.z));
                h4.w = f2bf(v.w); l4.w = f2bf(v.w - bf2f(h4.w));
                ((ushort4*)wo_hi)[k] = h4;
                ((ushort4*)wo_lo)[k] = l4;
            }
        }
        return;
    }
    const int n0 = blockIdx.x * 64;
    const int b  = blockIdx.z;
    const int t  = threadIdx.x;
    const int w = t >> 6, lane = t & 63, mcol = lane & 15, quad = lane >> 4;
    const int tx = t & 63, ty = t >> 6;

    __shared__ u16 X[64][260];            // [pos][chan]; dword pitch 130, rows 8B-aligned
    __shared__ float red[4][64];
    __shared__ float inv_s[64];
    __shared__ float gs[256];
    __shared__ float sqp[4][64], ndp[4][64];
    u16 (*Tt)[68] = (u16(*)[68])X;        // aliased after phase B

    // ---- phase A: rmsnorm, fmap held in registers (single global pass) ----
    gs[t] = gamma[t];
    const float* fb = fmap + (size_t)b * CC * NPOS;
    float v64[64];
#pragma unroll
    for (int i = 0; i < 64; ++i)
        v64[i] = fb[(ty * 64 + i) * NPOS + n0 + tx];
    float s = 0.0f;
#pragma unroll
    for (int i = 0; i < 64; ++i) s += v64[i] * v64[i];
    red[ty][tx] = s;
    __syncthreads();
    if (t < 64) {
        const float tt = red[0][t] + red[1][t] + red[2][t] + red[3][t];
        inv_s[t] = 16.0f / fmaxf(sqrtf(tt), 1e-12f);
    }
    __syncthreads();
    const float iv = inv_s[tx];
#pragma unroll
    for (int i = 0; i < 64; i += 2) {
        const int c = ty * 64 + i;
        const float v0 = v64[i] * iv * gs[c];
        const float v1 = v64[i + 1] * iv * gs[c + 1];
        *(u32*)&X[tx][c] = (u32)f2bf(v0) | ((u32)f2bf(v1) << 16);   // bank 2-way: free
    }
    if (blockIdx.x == 0 && oy == 0 && b == 0 && t < 8) {
        float s2 = 0.0f;
#pragma unroll 8
        for (int d = 0; d < 64; ++d) { const float x = null_kv[t * 64 + d]; s2 += x * x; }
        nk2b[t] = s2;
    }
    __syncthreads();

    // ---- phase B (dual): one X frag read feeds qk-head AND v-head MFMA ----
    const size_t wroff = (size_t)(oy * 64 + w * 16 + mcol) * 256 + quad * 8;
    const float* wrq = wqk + wroff;
    const float* wrv = wv + wroff;

    f32x4 cq[4], cv[4];
#pragma unroll
    for (int nf = 0; nf < 4; ++nf) {
        cq[nf] = (f32x4){0.f, 0.f, 0.f, 0.f};
        cv[nf] = (f32x4){0.f, 0.f, 0.f, 0.f};
    }
#pragma unroll
    for (int kc = 0; kc < 8; ++kc) {
        const float4 qa = *(const float4*)&wrq[kc * 32];
        const float4 qb4 = *(const float4*)&wrq[kc * 32 + 4];
        const float4 va = *(const float4*)&wrv[kc * 32];
        const float4 vb4 = *(const float4*)&wrv[kc * 32 + 4];
        bf16x8 aq, av;
        aq[0] = f2bf(qa.x);  aq[1] = f2bf(qa.y);  aq[2] = f2bf(qa.z);  aq[3] = f2bf(qa.w);
        aq[4] = f2bf(qb4.x); aq[5] = f2bf(qb4.y); aq[6] = f2bf(qb4.z); aq[7] = f2bf(qb4.w);
        av[0] = f2bf(va.x);  av[1] = f2bf(va.y);  av[2] = f2bf(va.z);  av[3] = f2bf(va.w);
        av[4] = f2bf(vb4.x); av[5] = f2bf(vb4.y); av[6] = f2bf(vb4.z); av[7] = f2bf(vb4.w);
        bf16x8 xB[4];
#pragma unroll
        for (int nf = 0; nf < 4; ++nf)
            xB[nf] = ld_x8(&X[nf * 16 + mcol][kc * 32 + quad * 8]);
#pragma unroll
        for (int nf = 0; nf < 4; ++nf) {
            cq[nf] = __builtin_amdgcn_mfma_f32_16x16x32_bf16(aq, xB[nf], cq[nf], 0, 0, 0);
            cv[nf] = __builtin_amdgcn_mfma_f32_16x16x32_bf16(av, xB[nf], cv[nf], 0, 0, 0);
        }
    }
    __syncthreads();   // all X reads done; Tt alias safe

    // ---- epilogue 1: qk head -> qkh + sq/ndot ----
    {
        const int h = oy;   // d = w*16 + quad*4 + r, n = n0 + nf*16 + mcol
        const float4 nk4 = *(const float4*)&null_kv[h * 64 + w * 16 + quad * 4];
        float sv[4], nd[4];
#pragma unroll
        for (int nf = 0; nf < 4; ++nf) {
            sv[nf] = cq[nf][0] * cq[nf][0] + cq[nf][1] * cq[nf][1] + cq[nf][2] * cq[nf][2] + cq[nf][3] * cq[nf][3];
            nd[nf] = cq[nf][0] * nk4.x + cq[nf][1] * nk4.y + cq[nf][2] * nk4.z + cq[nf][3] * nk4.w;
        }
#pragma unroll
        for (int mk = 16; mk <= 32; mk <<= 1)
#pragma unroll
            for (int nf = 0; nf < 4; ++nf) {
                sv[nf] += __shfl_xor(sv[nf], mk);
                nd[nf] += __shfl_xor(nd[nf], mk);
            }
        if (quad == 0) {
#pragma unroll
            for (int nf = 0; nf < 4; ++nf) {
                sqp[w][nf * 16 + mcol] = sv[nf];
                ndp[w][nf * 16 + mcol] = nd[nf];
            }
        }
#pragma unroll
        for (int nf = 0; nf < 4; ++nf) {
            ushort4 r4;
            r4.x = f2bf(cq[nf][0]); r4.y = f2bf(cq[nf][1]);
            r4.z = f2bf(cq[nf][2]); r4.w = f2bf(cq[nf][3]);
            *(ushort4*)&Tt[nf * 16 + mcol][w * 16 + quad * 4] = r4;   // Tt[n][d]
        }
        __syncthreads();
        {
            const int n = t >> 2, ds = (t & 3) * 16;
            const uint2 r0 = *(const uint2*)&Tt[n][ds + 0];
            const uint2 r1 = *(const uint2*)&Tt[n][ds + 4];
            const uint2 r2 = *(const uint2*)&Tt[n][ds + 8];
            const uint2 r3 = *(const uint2*)&Tt[n][ds + 12];
            u16* dst = qkh + (((size_t)b * 8 + h) * NPOS + n0 + n) * 64 + ds;
            *(uint4*)&dst[0] = make_uint4(r0.x, r0.y, r1.x, r1.y);
            *(uint4*)&dst[8] = make_uint4(r2.x, r2.y, r3.x, r3.y);
        }
        if (t < 64) {
            sq  [((size_t)b * 8 + h) * NPOS + n0 + t] = sqp[0][t] + sqp[1][t] + sqp[2][t] + sqp[3][t];
            ndot[((size_t)b * 8 + h) * NPOS + n0 + t] = ndp[0][t] + ndp[1][t] + ndp[2][t] + ndp[3][t];
        }
    }
    __syncthreads();   // qk readback done before Tt reuse

    // ---- epilogue 2: v head -> vt frag-ordered ----
    {
        const int h = oy;   // d = w*16+quad*4+r, key = n0 + nf*16 + mcol
#pragma unroll
        for (int nf = 0; nf < 4; ++nf)
#pragma unroll
            for (int r = 0; r < 4; ++r)
                Tt[w * 16 + quad * 4 + r][nf * 16 + mcol] = f2bf(cv[nf][r]);  // Tt[d][key]
        __syncthreads();
        {
            const int d = t >> 2, ks = t & 3;
            const uint2 a0 = *(const uint2*)&Tt[d][ks * 16 + 0];
            const uint2 a1 = *(const uint2*)&Tt[d][ks * 16 + 4];
            const uint2 a2 = *(const uint2*)&Tt[d][ks * 16 + 8];
            const uint2 a3 = *(const uint2*)&Tt[d][ks * 16 + 12];
            u16* vdst = vt + (size_t)(b * 8 + h) * (72 * 64 * 32);
            const int kb = blockIdx.x * 2 + (ks >> 1);
            u16* p = &vdst[((size_t)kb * 64 + d) * 32 + (ks & 1) * 16];
            *(uint4*)&p[0] = make_uint4(a0.x, a0.y, a1.x, a1.y);
            *(uint4*)&p[8] = make_uint4(a2.x, a2.y, a3.x, a3.y);
        }
    }
}

// ---------------- Kernel 2: K-split MFMA flash attention, 32 q/wave, XCD-swizzled ----------------
// (unchanged from R11 — measured floor of this structure at ~83 us)
__global__ __launch_bounds__(256) void k_attn(const u16* __restrict__ qkh,
                                              const u16* __restrict__ vt,
                                              const float* __restrict__ null_kv,
                                              const float* __restrict__ nk2b,
                                              const float* __restrict__ sq,
                                              const float* __restrict__ ndot,
                                              u16* __restrict__ ih,
                                              u16* __restrict__ il) {
    const int blk = blockIdx.x;
    const int xcd = blk & 7;
    const int j = blk >> 3;                 // 0..143
    const int bh = xcd * 2 + (j & 1);       // XCD-local bh pair
    const int qb = j >> 1;                  // 0..71
    const int q32 = qb * 32;
    const int tile0 = qb * 2;
    const int b = bh >> 3, h = bh & 7;
    const int t = threadIdx.x;
    const int wave = t >> 6, lane = t & 63;
    const int mcol = lane & 15, quad = lane >> 4;

    __shared__ __align__(16) char smem[18432];
    u16 (*Pt)[72] = (u16(*)[72])(smem + wave * 4608);

    const u16* qbase = qkh + (size_t)bh * NPOS * 64;
    const u16* vbase = vt + (size_t)bh * (72 * 64 * 32);
    const float* sqb = sq + (size_t)bh * NPOS;

    bf16x8 bq00, bq01, bq10, bq11;
    bq00 = *(const bf16x8*)&qbase[(q32 + mcol) * 64 + quad * 8];
    bq01 = *(const bf16x8*)&qbase[(q32 + mcol) * 64 + 32 + quad * 8];
    bq10 = *(const bf16x8*)&qbase[(q32 + 16 + mcol) * 64 + quad * 8];
    bq11 = *(const bf16x8*)&qbase[(q32 + 16 + mcol) * 64 + 32 + quad * 8];
    const float q2g0 = sqb[q32 + mcol];
    const float q2g1 = sqb[q32 + 16 + mcol];

    const bf16x8 ones = {0x3F80, 0x3F80, 0x3F80, 0x3F80, 0x3F80, 0x3F80, 0x3F80, 0x3F80};

    f32x4 oacc[2][4];
#pragma unroll
    for (int g = 0; g < 2; ++g)
#pragma unroll
        for (int nb = 0; nb < 4; ++nb) oacc[g][nb] = (f32x4){0.f, 0.f, 0.f, 0.f};
    f32x4 lsum0 = (f32x4){0.f, 0.f, 0.f, 0.f};
    f32x4 lsum1 = (f32x4){0.f, 0.f, 0.f, 0.f};

    const int kt0 = wave * 9;
#pragma unroll 2
    for (int k9 = 0; k9 < 9; ++k9) {
        const int kt = kt0 + k9;
        const int kj0 = kt * 64;

        bf16x8 bk[4][2], bv[4][2];
#pragma unroll
        for (int nb = 0; nb < 4; ++nb) {
            const u16* kr = &qbase[(kj0 + nb * 16 + mcol) * 64 + quad * 8];
            bk[nb][0] = *(const bf16x8*)&kr[0];
            bk[nb][1] = *(const bf16x8*)&kr[32];
        }
#pragma unroll
        for (int nb = 0; nb < 4; ++nb) {
            bv[nb][0] = *(const bf16x8*)&vbase[((size_t)(kt * 2 + 0) * 64 + nb * 16 + mcol) * 32 + quad * 8];
            bv[nb][1] = *(const bf16x8*)&vbase[((size_t)(kt * 2 + 1) * 64 + nb * 16 + mcol) * 32 + quad * 8];
        }
        float4 k2q[4];
#pragma unroll
        for (int nb = 0; nb < 4; ++nb)
            k2q[nb] = *(const float4*)&sqb[kj0 + nb * 16 + quad * 4];

        f32x4 c[2][4];
#pragma unroll
        for (int nb = 0; nb < 4; ++nb) {
            c[0][nb] = (f32x4){0.f, 0.f, 0.f, 0.f};
            c[0][nb] = __builtin_amdgcn_mfma_f32_16x16x32_bf16(bk[nb][0], bq00, c[0][nb], 0, 0, 0);
            c[0][nb] = __builtin_amdgcn_mfma_f32_16x16x32_bf16(bk[nb][1], bq01, c[0][nb], 0, 0, 0);
            c[1][nb] = (f32x4){0.f, 0.f, 0.f, 0.f};
            c[1][nb] = __builtin_amdgcn_mfma_f32_16x16x32_bf16(bk[nb][0], bq10, c[1][nb], 0, 0, 0);
            c[1][nb] = __builtin_amdgcn_mfma_f32_16x16x32_bf16(bk[nb][1], bq11, c[1][nb], 0, 0, 0);
        }

#pragma unroll
        for (int g = 0; g < 2; ++g) {
            const float q2 = g ? q2g1 : q2g0;
            const int ktm = (tile0 + g) >> 2, nbm = (tile0 + g) & 3;
#pragma unroll
            for (int nb = 0; nb < 4; ++nb) {
                float e[4];
#pragma unroll
                for (int r = 0; r < 4; ++r) {
                    const float pre = q2 + ((const float*)&k2q[nb])[r];
                    const float d2 = fmaxf(__builtin_fmaf(c[g][nb][r], -2.0f, pre), 0.0f);
                    e[r] = __builtin_amdgcn_exp2f(NEGSL2E * __builtin_amdgcn_sqrtf(d2));
                }
                if (kt == ktm && nb == nbm) {
#pragma unroll
                    for (int r = 0; r < 4; ++r)
                        if (quad * 4 + r == mcol) e[r] = 0.0f;   // exp(MASKV) ~ 0
                }
                const u32 p01 = __builtin_amdgcn_perm(__float_as_uint(e[1]), __float_as_uint(e[0]), 0x07060302u);
                const u32 p23 = __builtin_amdgcn_perm(__float_as_uint(e[3]), __float_as_uint(e[2]), 0x07060302u);
                *(uint2*)&Pt[g * 16 + mcol][nb * 16 + quad * 4] = make_uint2(p01, p23);
            }
        }

        const bf16x8 bp00 = *(const bf16x8*)&Pt[mcol][quad * 8];
        const bf16x8 bp01 = *(const bf16x8*)&Pt[mcol][32 + quad * 8];
        const bf16x8 bp10 = *(const bf16x8*)&Pt[16 + mcol][quad * 8];
        const bf16x8 bp11 = *(const bf16x8*)&Pt[16 + mcol][32 + quad * 8];

#pragma unroll
        for (int nb = 0; nb < 4; ++nb) {
            oacc[0][nb] = __builtin_amdgcn_mfma_f32_16x16x32_bf16(bv[nb][0], bp00, oacc[0][nb], 0, 0, 0);
            oacc[0][nb] = __builtin_amdgcn_mfma_f32_16x16x32_bf16(bv[nb][1], bp01, oacc[0][nb], 0, 0, 0);
            oacc[1][nb] = __builtin_amdgcn_mfma_f32_16x16x32_bf16(bv[nb][0], bp10, oacc[1][nb], 0, 0, 0);
            oacc[1][nb] = __builtin_amdgcn_mfma_f32_16x16x32_bf16(bv[nb][1], bp11, oacc[1][nb], 0, 0, 0);
        }
        lsum0 = __builtin_amdgcn_mfma_f32_16x16x32_bf16(ones, bp00, lsum0, 0, 0, 0);
        lsum0 = __builtin_amdgcn_mfma_f32_16x16x32_bf16(ones, bp01, lsum0, 0, 0, 0);
        lsum1 = __builtin_amdgcn_mfma_f32_16x16x32_bf16(ones, bp10, lsum1, 0, 0, 0);
        lsum1 = __builtin_amdgcn_mfma_f32_16x16x32_bf16(ones, bp11, lsum1, 0, 0, 0);
    }

    // ---- in-block cross-wave merge, 2 passes of 16 queries ----
    float* Of = (float*)smem;
    float* Ow = Of + wave * (16 * 66);
#pragma unroll
    for (int p = 0; p < 2; ++p) {
        __syncthreads();
#pragma unroll
        for (int nb = 0; nb < 4; ++nb)
#pragma unroll
            for (int r = 0; r < 4; ++r)
                Ow[mcol * 66 + nb * 16 + quad * 4 + r] = oacc[p][nb][r];
        if (quad == 0) Ow[mcol * 66 + 64] = p ? lsum1[0] : lsum0[0];
        __syncthreads();

        const int q = t >> 4;            // 0..15
        const int d0 = (t & 15) * 4;     // 0..60
        float o[4] = {0.f, 0.f, 0.f, 0.f};
        float l = 0.0f;
#pragma unroll
        for (int w = 0; w < 4; ++w) {
            const float* src = Of + w * (16 * 66) + q * 66;
            const float4 a = *(const float4*)&src[d0];
            o[0] += a.x; o[1] += a.y; o[2] += a.z; o[3] += a.w;
            l += src[64];
        }
        const int qg = q32 + p * 16 + q;
        const float q2v = sqb[qg];
        const float nd = ndot[(size_t)bh * NPOS + qg];
        const float nk2 = nk2b[h];
        const float d2n = fmaxf(q2v + nk2 - 2.0f * nd, 0.0f);
        const float beta = __expf(-sqrtf(d2n) * SCALE);
        const float ilv = 1.0f / (l + beta);

        const float4 nv4 = *(const float4*)&null_kv[DI + h * 64 + d0];
        float v[4];
        v[0] = (o[0] + beta * nv4.x) * ilv;
        v[1] = (o[1] + beta * nv4.y) * ilv;
        v[2] = (o[2] + beta * nv4.z) * ilv;
        v[3] = (o[3] + beta * nv4.w) * ilv;
        ushort4 hi4, lo4;
        hi4.x = f2bf(v[0]); lo4.x = f2bf(v[0] - bf2f(hi4.x));
        hi4.y = f2bf(v[1]); lo4.y = f2bf(v[1] - bf2f(hi4.y));
        hi4.z = f2bf(v[2]); lo4.z = f2bf(v[2] - bf2f(hi4.z));
        hi4.w = f2bf(v[3]); lo4.w = f2bf(v[3] - bf2f(hi4.w));
        const size_t ob = ((size_t)b * NPOS + qg) * DI + h * 64 + d0;
        *(ushort4*)&ih[ob] = hi4;
        *(ushort4*)&il[ob] = lo4;
    }
}

// ---------------- Kernel 3: output projection (split-bf16 MFMA, 32-wide j tiles) ----------------
__global__ __launch_bounds__(256) void k_out(const u16* __restrict__ wo_hi,
                                             const u16* __restrict__ wo_lo,
                                             const u16* __restrict__ ih,
                                             const u16* __restrict__ il,
                                             float* __restrict__ out) {
    const int j0 = blockIdx.x * 32;        // 72 j-tiles of 32 -> 576 blocks
    const int c0 = blockIdx.y * 64;
    const int b  = blockIdx.z;
    const int t  = threadIdx.x;
    const int w = t >> 6, lane = t & 63, mcol = lane & 15, quad = lane >> 4;

    const u16* ah = wo_hi + (size_t)(c0 + w * 16 + mcol) * 512 + quad * 8;
    const u16* al = wo_lo + (size_t)(c0 + w * 16 + mcol) * 512 + quad * 8;
    const u16* xh = ih + ((size_t)b * NPOS + j0 + mcol) * 512 + quad * 8;
    const u16* xl = il + ((size_t)b * NPOS + j0 + mcol) * 512 + quad * 8;

    f32x4 c[2];
#pragma unroll
    for (int nf = 0; nf < 2; ++nf) c[nf] = (f32x4){0.f, 0.f, 0.f, 0.f};
#pragma unroll
    for (int kc = 0; kc < 16; ++kc) {
        const bf16x8 A  = *(const bf16x8*)&ah[kc * 32];
        const bf16x8 Al = *(const bf16x8*)&al[kc * 32];
        bf16x8 Bh[2], Bl[2];
#pragma unroll
        for (int nf = 0; nf < 2; ++nf) {
            Bh[nf] = *(const bf16x8*)&xh[(size_t)nf * 16 * 512 + kc * 32];
            Bl[nf] = *(const bf16x8*)&xl[(size_t)nf * 16 * 512 + kc * 32];
        }
#pragma unroll
        for (int nf = 0; nf < 2; ++nf) {
            c[nf] = __builtin_amdgcn_mfma_f32_16x16x32_bf16(A,  Bh[nf], c[nf], 0, 0, 0);
            c[nf] = __builtin_amdgcn_mfma_f32_16x16x32_bf16(A,  Bl[nf], c[nf], 0, 0, 0);
            c[nf] = __builtin_amdgcn_mfma_f32_16x16x32_bf16(Al, Bh[nf], c[nf], 0, 0, 0);
        }
    }
    float* ob = out + ((size_t)b * CC + c0 + w * 16) * NPOS + j0;
#pragma unroll
    for (int nf = 0; nf < 2; ++nf)
#pragma unroll
        for (int r = 0; r < 4; ++r)
            ob[(size_t)(quad * 4 + r) * NPOS + nf * 16 + mcol] = c[nf][r];
}

extern "C" void kernel_launch(void* const* d_in, const int* in_sizes, int n_in,
                              void* d_out, int out_size, void* d_ws, size_t ws_size,
                              hipStream_t stream) {
    const float* fmap    = (const float*)d_in[0];
    const float* gamma   = (const float*)d_in[1];
    const float* w_qk    = (const float*)d_in[2];
    const float* w_v     = (const float*)d_in[3];
    const float* null_kv = (const float*)d_in[4];
    const float* w_out   = (const float*)d_in[5];
    float* out = (float*)d_out;

    u16* ws16 = (u16*)d_ws;
    u16* qkh    = ws16;                     // 16*2304*64  = 2,359,296 u16
    u16* vtb    = qkh + 2359296;            // 16*72*64*32 = 2,359,296
    u16* in_hi  = vtb + 2359296;            // 2*2304*512  = 2,359,296
    u16* in_lo  = in_hi + 2359296;          //               2,359,296
    u16* wo_hi  = in_lo + 2359296;          // 256*512     =   131,072
    u16* wo_lo  = wo_hi + 131072;           //                 131,072
    float* sqbuf = (float*)(wo_lo + 131072);    // 36,864 f32
    float* ndbuf = sqbuf + 36864;               // 36,864
    float* nk2b  = ndbuf + 36864;               // 8
    // total ~ 19.5 MB

    hipLaunchKernelGGL(k_proj, dim3(NT, 9, 2),  dim3(256), 0, stream,
                       fmap, gamma, w_qk, w_v, w_out, null_kv, qkh, vtb, sqbuf, ndbuf, nk2b, wo_hi, wo_lo);
    hipLaunchKernelGGL(k_attn, dim3(1152),      dim3(256), 0, stream,
                       qkh, vtb, null_kv, nk2b, sqbuf, ndbuf, in_hi, in_lo);
    hipLaunchKernelGGL(k_out,  dim3(72, 4, 2),  dim3(256), 0, stream,
                       wo_hi, wo_lo, in_hi, in_lo, out);
}

// Round 13
// 194.108 us; speedup vs baseline: 1.0486x; 1.0036x over previous
//
#include <hip/hip_runtime.h>
#include <math.h>

#define NPOS 2304   // 48*48
#define CC   256    // DIM
#define DI   512    // HEADS*DIM_HEAD
#define NT   36     // NPOS/64
#define SCALE 0.125f
#define MASKV -100.0f
// exp(-SCALE*sqrt(d2)) = exp2(-SCALE*log2(e)*sqrt(d2))
#define NEGSL2E (-0.18033688011112042f)

typedef __attribute__((ext_vector_type(8))) short bf16x8;  // 8 bf16 (4 VGPRs)
typedef __attribute__((ext_vector_type(4))) float f32x4;   // MFMA C/D frag
typedef unsigned short u16;
typedef unsigned int u32;

__device__ inline u16 f2bf(float f) {
    union { float f; unsigned int u; } v; v.f = f;
    return (u16)((v.u + 0x7fffu + ((v.u >> 16) & 1u)) >> 16);
}
__device__ inline float bf2f(u16 h) { return __uint_as_float(((u32)h) << 16); }

// assemble a bf16x8 frag from 8-byte-aligned LDS via two b64 reads
__device__ inline bf16x8 ld_x8(const u16* p) {
    union { bf16x8 v; uint2 d[2]; } u;
    u.d[0] = *(const uint2*)(p + 0);
    u.d[1] = *(const uint2*)(p + 4);
    return u.v;
}

// ---------------- Kernel 1: fused rmsnorm + paired qk/v MFMA projection ----------------
// XCD-aligned 1D grid: blk<576 -> xcd=blk&7 produces bh=xcd*2+(r&1), matching
// k_attn's consumer swizzle so each (b,h)'s qkh/vt/sq/ndot sit in the local L2.
// blk in [576,648): one-time w_out hi/lo split.
__global__ __launch_bounds__(256) void k_proj(const float* __restrict__ fmap,
                                              const float* __restrict__ gamma,
                                              const float* __restrict__ wqk,
                                              const float* __restrict__ wv,
                                              const float* __restrict__ wout,
                                              const float* __restrict__ null_kv,
                                              u16* __restrict__ qkh,
                                              u16* __restrict__ vt,
                                              float* __restrict__ sq,
                                              float* __restrict__ ndot,
                                              float* __restrict__ nk2b,
                                              u16* __restrict__ wo_hi,
                                              u16* __restrict__ wo_lo) {
    const int blk = blockIdx.x;
    if (blk >= 576) {                     // w_out hi/lo split (no LDS use, early out)
        const int idx = blk - 576;        // 0..71
#pragma unroll
        for (int it = 0; it < 2; ++it) {
            const int k = idx * 512 + (int)threadIdx.x + it * 256;
            if (k < 32768) {
                const float4 v = ((const float4*)wout)[k];
                ushort4 h4, l4;
                h4.x = f2bf(v.x); l4.x = f2bf(v.x - bf2f(h4.x));
                h4.y = f2bf(v.y); l4.y = f2bf(v.y - bf2f(h4.y));
                h4.z = f2bf(v.z); l4.z = f2bf(v.z - bf2f(h4.z));
                h4.w = f2bf(v.w); l4.w = f2bf(v.w - bf2f(h4.w));
                ((ushort4*)wo_hi)[k] = h4;
                ((ushort4*)wo_lo)[k] = l4;
            }
        }
        return;
    }
    // XCD-aligned decode: bh pair per XCD matches k_attn (bh = xcd*2 + parity)
    const int xcd = blk & 7;
    const int r   = blk >> 3;             // 0..71
    const int bh  = xcd * 2 + (r & 1);    // 0..15
    const int b   = bh >> 3;
    const int oy  = bh & 7;               // head
    const int n0  = (r >> 1) * 64;        // 36 position tiles

    const int t  = threadIdx.x;
    const int w = t >> 6, lane = t & 63, mcol = lane & 15, quad = lane >> 4;
    const int tx = t & 63, ty = t >> 6;

    __shared__ u16 X[64][260];            // [pos][chan]; dword pitch 130, rows 8B-aligned
    __shared__ float red[4][64];
    __shared__ float inv_s[64];
    __shared__ float gs[256];
    __shared__ float sqp[4][64], ndp[4][64];
    u16 (*Tt)[68] = (u16(*)[68])X;        // aliased after phase B

    // ---- phase A: rmsnorm, fmap held in registers (single global pass) ----
    gs[t] = gamma[t];
    const float* fb = fmap + (size_t)b * CC * NPOS;
    float v64[64];
#pragma unroll
    for (int i = 0; i < 64; ++i)
        v64[i] = fb[(ty * 64 + i) * NPOS + n0 + tx];
    float s = 0.0f;
#pragma unroll
    for (int i = 0; i < 64; ++i) s += v64[i] * v64[i];
    red[ty][tx] = s;
    __syncthreads();
    if (t < 64) {
        const float tt = red[0][t] + red[1][t] + red[2][t] + red[3][t];
        inv_s[t] = 16.0f / fmaxf(sqrtf(tt), 1e-12f);
    }
    __syncthreads();
    const float iv = inv_s[tx];
#pragma unroll
    for (int i = 0; i < 64; i += 2) {
        const int c = ty * 64 + i;
        const float v0 = v64[i] * iv * gs[c];
        const float v1 = v64[i + 1] * iv * gs[c + 1];
        *(u32*)&X[tx][c] = (u32)f2bf(v0) | ((u32)f2bf(v1) << 16);   // bank 2-way: free
    }
    if (blk == 0 && t < 8) {
        float s2 = 0.0f;
#pragma unroll 8
        for (int d = 0; d < 64; ++d) { const float x = null_kv[t * 64 + d]; s2 += x * x; }
        nk2b[t] = s2;
    }
    __syncthreads();

    // ---- phase B (dual): one X frag read feeds qk-head AND v-head MFMA ----
    const size_t wroff = (size_t)(oy * 64 + w * 16 + mcol) * 256 + quad * 8;
    const float* wrq = wqk + wroff;
    const float* wrv = wv + wroff;

    f32x4 cq[4], cv[4];
#pragma unroll
    for (int nf = 0; nf < 4; ++nf) {
        cq[nf] = (f32x4){0.f, 0.f, 0.f, 0.f};
        cv[nf] = (f32x4){0.f, 0.f, 0.f, 0.f};
    }
#pragma unroll
    for (int kc = 0; kc < 8; ++kc) {
        const float4 qa = *(const float4*)&wrq[kc * 32];
        const float4 qb4 = *(const float4*)&wrq[kc * 32 + 4];
        const float4 va = *(const float4*)&wrv[kc * 32];
        const float4 vb4 = *(const float4*)&wrv[kc * 32 + 4];
        bf16x8 aq, av;
        aq[0] = f2bf(qa.x);  aq[1] = f2bf(qa.y);  aq[2] = f2bf(qa.z);  aq[3] = f2bf(qa.w);
        aq[4] = f2bf(qb4.x); aq[5] = f2bf(qb4.y); aq[6] = f2bf(qb4.z); aq[7] = f2bf(qb4.w);
        av[0] = f2bf(va.x);  av[1] = f2bf(va.y);  av[2] = f2bf(va.z);  av[3] = f2bf(va.w);
        av[4] = f2bf(vb4.x); av[5] = f2bf(vb4.y); av[6] = f2bf(vb4.z); av[7] = f2bf(vb4.w);
        bf16x8 xB[4];
#pragma unroll
        for (int nf = 0; nf < 4; ++nf)
            xB[nf] = ld_x8(&X[nf * 16 + mcol][kc * 32 + quad * 8]);
#pragma unroll
        for (int nf = 0; nf < 4; ++nf) {
            cq[nf] = __builtin_amdgcn_mfma_f32_16x16x32_bf16(aq, xB[nf], cq[nf], 0, 0, 0);
            cv[nf] = __builtin_amdgcn_mfma_f32_16x16x32_bf16(av, xB[nf], cv[nf], 0, 0, 0);
        }
    }
    __syncthreads();   // all X reads done; Tt alias safe

    // ---- epilogue 1: qk head -> qkh + sq/ndot ----
    {
        const int h = oy;   // d = w*16 + quad*4 + r, n = n0 + nf*16 + mcol
        const float4 nk4 = *(const float4*)&null_kv[h * 64 + w * 16 + quad * 4];
        float sv[4], nd[4];
#pragma unroll
        for (int nf = 0; nf < 4; ++nf) {
            sv[nf] = cq[nf][0] * cq[nf][0] + cq[nf][1] * cq[nf][1] + cq[nf][2] * cq[nf][2] + cq[nf][3] * cq[nf][3];
            nd[nf] = cq[nf][0] * nk4.x + cq[nf][1] * nk4.y + cq[nf][2] * nk4.z + cq[nf][3] * nk4.w;
        }
#pragma unroll
        for (int mk = 16; mk <= 32; mk <<= 1)
#pragma unroll
            for (int nf = 0; nf < 4; ++nf) {
                sv[nf] += __shfl_xor(sv[nf], mk);
                nd[nf] += __shfl_xor(nd[nf], mk);
            }
        if (quad == 0) {
#pragma unroll
            for (int nf = 0; nf < 4; ++nf) {
                sqp[w][nf * 16 + mcol] = sv[nf];
                ndp[w][nf * 16 + mcol] = nd[nf];
            }
        }
#pragma unroll
        for (int nf = 0; nf < 4; ++nf) {
            ushort4 r4;
            r4.x = f2bf(cq[nf][0]); r4.y = f2bf(cq[nf][1]);
            r4.z = f2bf(cq[nf][2]); r4.w = f2bf(cq[nf][3]);
            *(ushort4*)&Tt[nf * 16 + mcol][w * 16 + quad * 4] = r4;   // Tt[n][d]
        }
        __syncthreads();
        {
            const int n = t >> 2, ds = (t & 3) * 16;
            const uint2 r0 = *(const uint2*)&Tt[n][ds + 0];
            const uint2 r1 = *(const uint2*)&Tt[n][ds + 4];
            const uint2 r2 = *(const uint2*)&Tt[n][ds + 8];
            const uint2 r3 = *(const uint2*)&Tt[n][ds + 12];
            u16* dst = qkh + (((size_t)bh) * NPOS + n0 + n) * 64 + ds;
            *(uint4*)&dst[0] = make_uint4(r0.x, r0.y, r1.x, r1.y);
            *(uint4*)&dst[8] = make_uint4(r2.x, r2.y, r3.x, r3.y);
        }
        if (t < 64) {
            sq  [((size_t)bh) * NPOS + n0 + t] = sqp[0][t] + sqp[1][t] + sqp[2][t] + sqp[3][t];
            ndot[((size_t)bh) * NPOS + n0 + t] = ndp[0][t] + ndp[1][t] + ndp[2][t] + ndp[3][t];
        }
    }
    __syncthreads();   // qk readback done before Tt reuse

    // ---- epilogue 2: v head -> vt frag-ordered ----
    {
#pragma unroll
        for (int nf = 0; nf < 4; ++nf)
#pragma unroll
            for (int rr = 0; rr < 4; ++rr)
                Tt[w * 16 + quad * 4 + rr][nf * 16 + mcol] = f2bf(cv[nf][rr]);  // Tt[d][key]
        __syncthreads();
        {
            const int d = t >> 2, ks = t & 3;
            const uint2 a0 = *(const uint2*)&Tt[d][ks * 16 + 0];
            const uint2 a1 = *(const uint2*)&Tt[d][ks * 16 + 4];
            const uint2 a2 = *(const uint2*)&Tt[d][ks * 16 + 8];
            const uint2 a3 = *(const uint2*)&Tt[d][ks * 16 + 12];
            u16* vdst = vt + (size_t)bh * (72 * 64 * 32);
            const int kb = (n0 >> 5) + (ks >> 1);
            u16* p = &vdst[((size_t)kb * 64 + d) * 32 + (ks & 1) * 16];
            *(uint4*)&p[0] = make_uint4(a0.x, a0.y, a1.x, a1.y);
            *(uint4*)&p[8] = make_uint4(a2.x, a2.y, a3.x, a3.y);
        }
    }
}

// ---------------- Kernel 2: K-split MFMA flash attention, 32 q/wave, XCD-swizzled ----------------
// (unchanged from R11/R12)
__global__ __launch_bounds__(256) void k_attn(const u16* __restrict__ qkh,
                                              const u16* __restrict__ vt,
                                              const float* __restrict__ null_kv,
                                              const float* __restrict__ nk2b,
                                              const float* __restrict__ sq,
                                              const float* __restrict__ ndot,
                                              u16* __restrict__ ih,
                                              u16* __restrict__ il) {
    const int blk = blockIdx.x;
    const int xcd = blk & 7;
    const int j = blk >> 3;                 // 0..143
    const int bh = xcd * 2 + (j & 1);       // XCD-local bh pair
    const int qb = j >> 1;                  // 0..71
    const int q32 = qb * 32;
    const int tile0 = qb * 2;
    const int b = bh >> 3, h = bh & 7;
    const int t = threadIdx.x;
    const int wave = t >> 6, lane = t & 63;
    const int mcol = lane & 15, quad = lane >> 4;

    __shared__ __align__(16) char smem[18432];
    u16 (*Pt)[72] = (u16(*)[72])(smem + wave * 4608);

    const u16* qbase = qkh + (size_t)bh * NPOS * 64;
    const u16* vbase = vt + (size_t)bh * (72 * 64 * 32);
    const float* sqb = sq + (size_t)bh * NPOS;

    bf16x8 bq00, bq01, bq10, bq11;
    bq00 = *(const bf16x8*)&qbase[(q32 + mcol) * 64 + quad * 8];
    bq01 = *(const bf16x8*)&qbase[(q32 + mcol) * 64 + 32 + quad * 8];
    bq10 = *(const bf16x8*)&qbase[(q32 + 16 + mcol) * 64 + quad * 8];
    bq11 = *(const bf16x8*)&qbase[(q32 + 16 + mcol) * 64 + 32 + quad * 8];
    const float q2g0 = sqb[q32 + mcol];
    const float q2g1 = sqb[q32 + 16 + mcol];

    const bf16x8 ones = {0x3F80, 0x3F80, 0x3F80, 0x3F80, 0x3F80, 0x3F80, 0x3F80, 0x3F80};

    f32x4 oacc[2][4];
#pragma unroll
    for (int g = 0; g < 2; ++g)
#pragma unroll
        for (int nb = 0; nb < 4; ++nb) oacc[g][nb] = (f32x4){0.f, 0.f, 0.f, 0.f};
    f32x4 lsum0 = (f32x4){0.f, 0.f, 0.f, 0.f};
    f32x4 lsum1 = (f32x4){0.f, 0.f, 0.f, 0.f};

    const int kt0 = wave * 9;
#pragma unroll 2
    for (int k9 = 0; k9 < 9; ++k9) {
        const int kt = kt0 + k9;
        const int kj0 = kt * 64;

        bf16x8 bk[4][2], bv[4][2];
#pragma unroll
        for (int nb = 0; nb < 4; ++nb) {
            const u16* kr = &qbase[(kj0 + nb * 16 + mcol) * 64 + quad * 8];
            bk[nb][0] = *(const bf16x8*)&kr[0];
            bk[nb][1] = *(const bf16x8*)&kr[32];
        }
#pragma unroll
        for (int nb = 0; nb < 4; ++nb) {
            bv[nb][0] = *(const bf16x8*)&vbase[((size_t)(kt * 2 + 0) * 64 + nb * 16 + mcol) * 32 + quad * 8];
            bv[nb][1] = *(const bf16x8*)&vbase[((size_t)(kt * 2 + 1) * 64 + nb * 16 + mcol) * 32 + quad * 8];
        }
        float4 k2q[4];
#pragma unroll
        for (int nb = 0; nb < 4; ++nb)
            k2q[nb] = *(const float4*)&sqb[kj0 + nb * 16 + quad * 4];

        f32x4 c[2][4];
#pragma unroll
        for (int nb = 0; nb < 4; ++nb) {
            c[0][nb] = (f32x4){0.f, 0.f, 0.f, 0.f};
            c[0][nb] = __builtin_amdgcn_mfma_f32_16x16x32_bf16(bk[nb][0], bq00, c[0][nb], 0, 0, 0);
            c[0][nb] = __builtin_amdgcn_mfma_f32_16x16x32_bf16(bk[nb][1], bq01, c[0][nb], 0, 0, 0);
            c[1][nb] = (f32x4){0.f, 0.f, 0.f, 0.f};
            c[1][nb] = __builtin_amdgcn_mfma_f32_16x16x32_bf16(bk[nb][0], bq10, c[1][nb], 0, 0, 0);
            c[1][nb] = __builtin_amdgcn_mfma_f32_16x16x32_bf16(bk[nb][1], bq11, c[1][nb], 0, 0, 0);
        }

#pragma unroll
        for (int g = 0; g < 2; ++g) {
            const float q2 = g ? q2g1 : q2g0;
            const int ktm = (tile0 + g) >> 2, nbm = (tile0 + g) & 3;
#pragma unroll
            for (int nb = 0; nb < 4; ++nb) {
                float e[4];
#pragma unroll
                for (int r = 0; r < 4; ++r) {
                    const float pre = q2 + ((const float*)&k2q[nb])[r];
                    const float d2 = fmaxf(__builtin_fmaf(c[g][nb][r], -2.0f, pre), 0.0f);
                    e[r] = __builtin_amdgcn_exp2f(NEGSL2E * __builtin_amdgcn_sqrtf(d2));
                }
                if (kt == ktm && nb == nbm) {
#pragma unroll
                    for (int r = 0; r < 4; ++r)
                        if (quad * 4 + r == mcol) e[r] = 0.0f;   // exp(MASKV) ~ 0
                }
                const u32 p01 = __builtin_amdgcn_perm(__float_as_uint(e[1]), __float_as_uint(e[0]), 0x07060302u);
                const u32 p23 = __builtin_amdgcn_perm(__float_as_uint(e[3]), __float_as_uint(e[2]), 0x07060302u);
                *(uint2*)&Pt[g * 16 + mcol][nb * 16 + quad * 4] = make_uint2(p01, p23);
            }
        }

        const bf16x8 bp00 = *(const bf16x8*)&Pt[mcol][quad * 8];
        const bf16x8 bp01 = *(const bf16x8*)&Pt[mcol][32 + quad * 8];
        const bf16x8 bp10 = *(const bf16x8*)&Pt[16 + mcol][quad * 8];
        const bf16x8 bp11 = *(const bf16x8*)&Pt[16 + mcol][32 + quad * 8];

#pragma unroll
        for (int nb = 0; nb < 4; ++nb) {
            oacc[0][nb] = __builtin_amdgcn_mfma_f32_16x16x32_bf16(bv[nb][0], bp00, oacc[0][nb], 0, 0, 0);
            oacc[0][nb] = __builtin_amdgcn_mfma_f32_16x16x32_bf16(bv[nb][1], bp01, oacc[0][nb], 0, 0, 0);
            oacc[1][nb] = __builtin_amdgcn_mfma_f32_16x16x32_bf16(bv[nb][0], bp10, oacc[1][nb], 0, 0, 0);
            oacc[1][nb] = __builtin_amdgcn_mfma_f32_16x16x32_bf16(bv[nb][1], bp11, oacc[1][nb], 0, 0, 0);
        }
        lsum0 = __builtin_amdgcn_mfma_f32_16x16x32_bf16(ones, bp00, lsum0, 0, 0, 0);
        lsum0 = __builtin_amdgcn_mfma_f32_16x16x32_bf16(ones, bp01, lsum0, 0, 0, 0);
        lsum1 = __builtin_amdgcn_mfma_f32_16x16x32_bf16(ones, bp10, lsum1, 0, 0, 0);
        lsum1 = __builtin_amdgcn_mfma_f32_16x16x32_bf16(ones, bp11, lsum1, 0, 0, 0);
    }

    // ---- in-block cross-wave merge, 2 passes of 16 queries ----
    float* Of = (float*)smem;
    float* Ow = Of + wave * (16 * 66);
#pragma unroll
    for (int p = 0; p < 2; ++p) {
        __syncthreads();
#pragma unroll
        for (int nb = 0; nb < 4; ++nb)
#pragma unroll
            for (int r = 0; r < 4; ++r)
                Ow[mcol * 66 + nb * 16 + quad * 4 + r] = oacc[p][nb][r];
        if (quad == 0) Ow[mcol * 66 + 64] = p ? lsum1[0] : lsum0[0];
        __syncthreads();

        const int q = t >> 4;            // 0..15
        const int d0 = (t & 15) * 4;     // 0..60
        float o[4] = {0.f, 0.f, 0.f, 0.f};
        float l = 0.0f;
#pragma unroll
        for (int w = 0; w < 4; ++w) {
            const float* src = Of + w * (16 * 66) + q * 66;
            const float4 a = *(const float4*)&src[d0];
            o[0] += a.x; o[1] += a.y; o[2] += a.z; o[3] += a.w;
            l += src[64];
        }
        const int qg = q32 + p * 16 + q;
        const float q2v = sqb[qg];
        const float nd = ndot[(size_t)bh * NPOS + qg];
        const float nk2 = nk2b[h];
        const float d2n = fmaxf(q2v + nk2 - 2.0f * nd, 0.0f);
        const float beta = __expf(-sqrtf(d2n) * SCALE);
        const float ilv = 1.0f / (l + beta);

        const float4 nv4 = *(const float4*)&null_kv[DI + h * 64 + d0];
        float v[4];
        v[0] = (o[0] + beta * nv4.x) * ilv;
        v[1] = (o[1] + beta * nv4.y) * ilv;
        v[2] = (o[2] + beta * nv4.z) * ilv;
        v[3] = (o[3] + beta * nv4.w) * ilv;
        ushort4 hi4, lo4;
        hi4.x = f2bf(v[0]); lo4.x = f2bf(v[0] - bf2f(hi4.x));
        hi4.y = f2bf(v[1]); lo4.y = f2bf(v[1] - bf2f(hi4.y));
        hi4.z = f2bf(v[2]); lo4.z = f2bf(v[2] - bf2f(hi4.z));
        hi4.w = f2bf(v[3]); lo4.w = f2bf(v[3] - bf2f(hi4.w));
        const size_t ob = ((size_t)b * NPOS + qg) * DI + h * 64 + d0;
        *(ushort4*)&ih[ob] = hi4;
        *(ushort4*)&il[ob] = lo4;
    }
}

// ---------------- Kernel 3: output projection (split-bf16 MFMA, 32-wide j tiles) ----------------
__global__ __launch_bounds__(256) void k_out(const u16* __restrict__ wo_hi,
                                             const u16* __restrict__ wo_lo,
                                             const u16* __restrict__ ih,
                                             const u16* __restrict__ il,
                                             float* __restrict__ out) {
    const int j0 = blockIdx.x * 32;        // 72 j-tiles of 32 -> 576 blocks
    const int c0 = blockIdx.y * 64;
    const int b  = blockIdx.z;
    const int t  = threadIdx.x;
    const int w = t >> 6, lane = t & 63, mcol = lane & 15, quad = lane >> 4;

    const u16* ah = wo_hi + (size_t)(c0 + w * 16 + mcol) * 512 + quad * 8;
    const u16* al = wo_lo + (size_t)(c0 + w * 16 + mcol) * 512 + quad * 8;
    const u16* xh = ih + ((size_t)b * NPOS + j0 + mcol) * 512 + quad * 8;
    const u16* xl = il + ((size_t)b * NPOS + j0 + mcol) * 512 + quad * 8;

    f32x4 c[2];
#pragma unroll
    for (int nf = 0; nf < 2; ++nf) c[nf] = (f32x4){0.f, 0.f, 0.f, 0.f};
#pragma unroll
    for (int kc = 0; kc < 16; ++kc) {
        const bf16x8 A  = *(const bf16x8*)&ah[kc * 32];
        const bf16x8 Al = *(const bf16x8*)&al[kc * 32];
        bf16x8 Bh[2], Bl[2];
#pragma unroll
        for (int nf = 0; nf < 2; ++nf) {
            Bh[nf] = *(const bf16x8*)&xh[(size_t)nf * 16 * 512 + kc * 32];
            Bl[nf] = *(const bf16x8*)&xl[(size_t)nf * 16 * 512 + kc * 32];
        }
#pragma unroll
        for (int nf = 0; nf < 2; ++nf) {
            c[nf] = __builtin_amdgcn_mfma_f32_16x16x32_bf16(A,  Bh[nf], c[nf], 0, 0, 0);
            c[nf] = __builtin_amdgcn_mfma_f32_16x16x32_bf16(A,  Bl[nf], c[nf], 0, 0, 0);
            c[nf] = __builtin_amdgcn_mfma_f32_16x16x32_bf16(Al, Bh[nf], c[nf], 0, 0, 0);
        }
    }
    float* ob = out + ((size_t)b * CC + c0 + w * 16) * NPOS + j0;
#pragma unroll
    for (int nf = 0; nf < 2; ++nf)
#pragma unroll
        for (int r = 0; r < 4; ++r)
            ob[(size_t)(quad * 4 + r) * NPOS + nf * 16 + mcol] = c[nf][r];
}

extern "C" void kernel_launch(void* const* d_in, const int* in_sizes, int n_in,
                              void* d_out, int out_size, void* d_ws, size_t ws_size,
                              hipStream_t stream) {
    const float* fmap    = (const float*)d_in[0];
    const float* gamma   = (const float*)d_in[1];
    const float* w_qk    = (const float*)d_in[2];
    const float* w_v     = (const float*)d_in[3];
    const float* null_kv = (const float*)d_in[4];
    const float* w_out   = (const float*)d_in[5];
    float* out = (float*)d_out;

    u16* ws16 = (u16*)d_ws;
    u16* qkh    = ws16;                     // 16*2304*64  = 2,359,296 u16
    u16* vtb    = qkh + 2359296;            // 16*72*64*32 = 2,359,296
    u16* in_hi  = vtb + 2359296;            // 2*2304*512  = 2,359,296
    u16* in_lo  = in_hi + 2359296;          //               2,359,296
    u16* wo_hi  = in_lo + 2359296;          // 256*512     =   131,072
    u16* wo_lo  = wo_hi + 131072;           //                 131,072
    float* sqbuf = (float*)(wo_lo + 131072);    // 36,864 f32
    float* ndbuf = sqbuf + 36864;               // 36,864
    float* nk2b  = ndbuf + 36864;               // 8
    // total ~ 19.5 MB

    hipLaunchKernelGGL(k_proj, dim3(648),       dim3(256), 0, stream,
                       fmap, gamma, w_qk, w_v, w_out, null_kv, qkh, vtb, sqbuf, ndbuf, nk2b, wo_hi, wo_lo);
    hipLaunchKernelGGL(k_attn, dim3(1152),      dim3(256), 0, stream,
                       qkh, vtb, null_kv, nk2b, sqbuf, ndbuf, in_hi, in_lo);
    hipLaunchKernelGGL(k_out,  dim3(72, 4, 2),  dim3(256), 0, stream,
                       wo_hi, wo_lo, in_hi, in_lo, out);
}